// Round 1
// baseline (288.406 us; speedup 1.0000x reference)
//
#include <hip/hip_runtime.h>

// TinyDLRM: out[i] = sigmoid( relu( f @ w1 + b1 ) @ w2 + b2 )
// f = [user_emb(8) | item_emb(8) | cat_emb(8) | dense(2)]  (26 floats)
//
// Strategy v1: one thread per sample. Weights (w1: 26x16, b1, w2, b2) are
// read with wave-uniform indices straight from global memory so the compiler
// emits s_load -> SGPRs and v_fma_f32 with an SGPR operand (no LDS: a
// per-lane LDS read of all 416 w1 floats would be LDS-return-bandwidth bound
// at ~104 ds_read_b128 per wave > the 832 VALU cycles of the FMAs).

#define HIDDEN 16
#define IN_DIM 26

__global__ __launch_bounds__(256) void tiny_dlrm_kernel(
    const int*   __restrict__ user_id,
    const int*   __restrict__ item_id,
    const int*   __restrict__ cat_id,
    const float* __restrict__ dense,      // [B,2]
    const float* __restrict__ user_table, // [NU,8]
    const float* __restrict__ item_table, // [NI,8]
    const float* __restrict__ cat_table,  // [NC,8]
    const float* __restrict__ w1,         // [26,16] row-major
    const float* __restrict__ b1,         // [16]
    const float* __restrict__ w2,         // [16]
    const float* __restrict__ b2,         // [1]
    float*       __restrict__ out,        // [B]
    int batch)
{
    int i = blockIdx.x * blockDim.x + threadIdx.x;
    if (i >= batch) return;

    // --- gather ---
    int u = user_id[i];
    int v = item_id[i];
    int c = cat_id[i];

    const float4* up = (const float4*)(user_table + (size_t)u * 8);
    const float4* ip = (const float4*)(item_table + (size_t)v * 8);
    const float4* cp = (const float4*)(cat_table  + (size_t)c * 8);
    float4 u0 = up[0], u1 = up[1];
    float4 i0 = ip[0], i1 = ip[1];
    float4 c0 = cp[0], c1 = cp[1];
    float2 dd = ((const float2*)dense)[i];

    float f[IN_DIM] = {
        u0.x, u0.y, u0.z, u0.w, u1.x, u1.y, u1.z, u1.w,
        i0.x, i0.y, i0.z, i0.w, i1.x, i1.y, i1.z, i1.w,
        c0.x, c0.y, c0.z, c0.w, c1.x, c1.y, c1.z, c1.w,
        dd.x, dd.y
    };

    // --- layer 1: h = f @ w1 + b1 (w1 accesses are wave-uniform -> SGPRs) ---
    float h[HIDDEN];
#pragma unroll
    for (int j = 0; j < HIDDEN; ++j) h[j] = b1[j];

#pragma unroll
    for (int k = 0; k < IN_DIM; ++k) {
        float fk = f[k];
#pragma unroll
        for (int j = 0; j < HIDDEN; ++j) {
            h[j] = fmaf(fk, w1[k * HIDDEN + j], h[j]);
        }
    }

    // --- layer 2: logits = relu(h) @ w2 + b2; sigmoid ---
    float acc = b2[0];
#pragma unroll
    for (int j = 0; j < HIDDEN; ++j) {
        acc = fmaf(fmaxf(h[j], 0.0f), w2[j], acc);
    }

    out[i] = 1.0f / (1.0f + __expf(-acc));
}

extern "C" void kernel_launch(void* const* d_in, const int* in_sizes, int n_in,
                              void* d_out, int out_size, void* d_ws, size_t ws_size,
                              hipStream_t stream) {
    const int*   user_id    = (const int*)d_in[0];
    const int*   item_id    = (const int*)d_in[1];
    const int*   cat_id     = (const int*)d_in[2];
    const float* dense      = (const float*)d_in[3];
    const float* user_table = (const float*)d_in[4];
    const float* item_table = (const float*)d_in[5];
    const float* cat_table  = (const float*)d_in[6];
    const float* w1         = (const float*)d_in[7];
    const float* b1         = (const float*)d_in[8];
    const float* w2         = (const float*)d_in[9];
    const float* b2         = (const float*)d_in[10];
    float* out = (float*)d_out;

    int batch = in_sizes[0];
    int block = 256;
    int grid = (batch + block - 1) / block;
    tiny_dlrm_kernel<<<grid, block, 0, stream>>>(
        user_id, item_id, cat_id, dense,
        user_table, item_table, cat_table,
        w1, b1, w2, b2, out, batch);
}